// Round 17
// baseline (89.641 us; speedup 1.0000x reference)
//
#include <hip/hip_runtime.h>
#include <math.h>

#define BB 128
#define HH 768
#define KQ 32768
#define PCAP 18432  // max positives per row staged in LDS
#define NB 4096     // histogram bins
#define CCAP 512    // candidate cap per target bin

constexpr float TINV = 1.0f / 0.07f;

typedef __attribute__((ext_vector_type(8))) short short8;
typedef __attribute__((ext_vector_type(4))) float f32x4;
typedef __attribute__((address_space(3))) void lds_void;
typedef const __attribute__((address_space(1))) void gbl_void;

__device__ __forceinline__ unsigned short f2bf(float f) {
  unsigned u = __float_as_uint(f);
  unsigned r = u + 0x7FFFu + ((u >> 16) & 1u);  // RNE
  return (unsigned short)(r >> 16);
}
__device__ __forceinline__ float bf2f(unsigned short h) {
  return __uint_as_float(((unsigned)h) << 16);
}
__device__ __forceinline__ unsigned cvtpk(float a, float b) {
  unsigned r;
  asm("v_cvt_pk_bf16_f32 %0, %1, %2" : "=v"(r) : "v"(a), "v"(b));
  return r;
}
__device__ __forceinline__ unsigned f2key(float f) {
  unsigned u = __float_as_uint(f);
  return u ^ (unsigned)(((int)u >> 31) | 0x80000000);
}
__device__ __forceinline__ float key2f(unsigned k) {
  unsigned u = (k & 0x80000000u) ? (k & 0x7FFFFFFFu) : ~k;
  return __uint_as_float(u);
}
__device__ __forceinline__ unsigned long long shfl_down_u64(unsigned long long v, int o) {
  unsigned lo = (unsigned)v, hi = (unsigned)(v >> 32);
  lo = __shfl_down(lo, o);
  hi = __shfl_down(hi, o);
  return ((unsigned long long)hi << 32) | lo;
}
__device__ __forceinline__ void gl16(const unsigned short* g, unsigned short* l) {
  __builtin_amdgcn_global_load_lds((gbl_void*)g, (lds_void*)l, 16, 0, 0);
}

// prep: bid<432 -> transpose W{0,1,2} (768x768 f32) into Wt (bf16, [n][k]);
//       bid>=432 -> pooled f32 -> bf16. Block 0 zeroes out[0].
__global__ __launch_bounds__(256) void prep_kernel(
    const float* __restrict__ W0, const float* __restrict__ W1,
    const float* __restrict__ W2, const float* __restrict__ pooled,
    unsigned short* __restrict__ Wt0, unsigned short* __restrict__ Wt1,
    unsigned short* __restrict__ Wt2, unsigned short* __restrict__ pooledb,
    float* __restrict__ out) {
  const int bid = blockIdx.x, tid = threadIdx.x;
  if (bid == 0 && tid == 0) out[0] = 0.0f;
  if (bid < 432) {
    const float* W = (bid < 144) ? W0 : (bid < 288 ? W1 : W2);
    unsigned short* Wt = (bid < 144) ? Wt0 : (bid < 288 ? Wt1 : Wt2);
    const int t = bid % 144;
    const int k0 = (t / 12) * 64, n0 = (t % 12) * 64;
    __shared__ float Ls[64][65];
    const int r = tid >> 4, c4 = (tid & 15) * 4;
#pragma unroll
    for (int i = 0; i < 4; ++i) {
      const int rr = r + i * 16;
      const float4 v = *reinterpret_cast<const float4*>(W + (size_t)(k0 + rr) * HH + n0 + c4);
      Ls[rr][c4 + 0] = v.x; Ls[rr][c4 + 1] = v.y;
      Ls[rr][c4 + 2] = v.z; Ls[rr][c4 + 3] = v.w;
    }
    __syncthreads();
#pragma unroll
    for (int i = 0; i < 4; ++i) {
      const int rn = r + i * 16;  // n-local
      ushort4 o;
      o.x = f2bf(Ls[c4 + 0][rn]);
      o.y = f2bf(Ls[c4 + 1][rn]);
      o.z = f2bf(Ls[c4 + 2][rn]);
      o.w = f2bf(Ls[c4 + 3][rn]);
      *reinterpret_cast<ushort4*>(Wt + (size_t)(n0 + rn) * HH + k0 + c4) = o;
    }
  } else {
    const int idx = (bid - 432) * 1024 + tid * 4;
    const float4 v = *reinterpret_cast<const float4*>(pooled + idx);
    ushort4 o;
    o.x = f2bf(v.x); o.y = f2bf(v.y); o.z = f2bf(v.z); o.w = f2bf(v.w);
    *reinterpret_cast<ushort4*>(pooledb + idx) = o;
  }
}

// MFMA head GEMM core: Out[128,768](bf16) cols [q0,q0+64) =
//   act(Ab[128,768](bf16) @ Wt^T + bias). Tri-buffered gl16 A-staging,
//   counted-vmcnt, B = direct 16B bf16 loads (1/step).
__device__ __forceinline__ void head_core(
    unsigned short (*Abuf)[128 * 64], const unsigned short* __restrict__ Ab,
    const unsigned short* __restrict__ Wt, const float* __restrict__ bias,
    unsigned short* __restrict__ Out, bool do_tanh, int q0, int tid) {
  const int lane = tid & 63, wid = tid >> 6;
  const int a_r = lane & 15, a_kq = lane >> 4;
  int asrc[4], adst[4];
#pragma unroll
  for (int j = 0; j < 4; ++j) {
    const int rr = (wid * 4 + j) * 8 + (lane >> 3);
    const int kb = (lane & 7) ^ (rr & 7);
    asrc[j] = rr * HH + kb * 8;
    adst[j] = (wid * 4 + j) * 512;
  }
  const int bn = q0 + wid * 16 + a_r;
  const unsigned short* __restrict__ bptr = Wt + (size_t)bn * HH + a_kq * 8;
  int aslot[2];
#pragma unroll
  for (int st = 0; st < 2; ++st) aslot[st] = (((st * 4 + a_kq) ^ (a_r & 7)) << 3);

  f32x4 acc[8];
#pragma unroll
  for (int m = 0; m < 8; ++m) acc[m] = (f32x4){0.f, 0.f, 0.f, 0.f};

#pragma unroll
  for (int j = 0; j < 4; ++j) gl16(Ab + asrc[j], &Abuf[0][adst[j]]);
  __builtin_amdgcn_sched_barrier(0);
#pragma unroll
  for (int j = 0; j < 4; ++j) gl16(Ab + 64 + asrc[j], &Abuf[1][adst[j]]);
  __builtin_amdgcn_sched_barrier(0);
  short8 bv[4];
#pragma unroll
  for (int p = 0; p < 4; ++p)
    bv[p] = *reinterpret_cast<const short8*>(bptr + p * 32);
  __builtin_amdgcn_sched_barrier(0);
  asm volatile("s_waitcnt vmcnt(8)" ::: "memory");  // G0 retired
  __builtin_amdgcn_s_barrier();
  __builtin_amdgcn_sched_barrier(0);

#pragma unroll
  for (int c = 0; c < 12; ++c) {
    if (c + 2 < 12) {
#pragma unroll
      for (int j = 0; j < 4; ++j)
        gl16(Ab + (c + 2) * 64 + asrc[j], &Abuf[(c + 2) % 3][adst[j]]);
    }
    __builtin_amdgcn_sched_barrier(0);
    const unsigned short* __restrict__ Abc = Abuf[c % 3];
#pragma unroll
    for (int st = 0; st < 2; ++st) {
      const int s = c * 2 + st;
      const short8 bb = bv[s & 3];
      if (s + 4 < 24)
        bv[s & 3] = *reinterpret_cast<const short8*>(bptr + (s + 4) * 32);
      const int sl = aslot[st];
#pragma unroll
      for (int m = 0; m < 8; ++m) {
        const short8 aa =
            *reinterpret_cast<const short8*>(&Abc[(m * 16 + a_r) * 64 + sl]);
        acc[m] = __builtin_amdgcn_mfma_f32_16x16x32_bf16(aa, bb, acc[m], 0, 0, 0);
      }
    }
    if (c < 11) {
      __builtin_amdgcn_sched_barrier(0);
      if (c == 0)       asm volatile("s_waitcnt vmcnt(10)" ::: "memory");
      else if (c <= 9)  asm volatile("s_waitcnt vmcnt(8)" ::: "memory");
      else              asm volatile("s_waitcnt vmcnt(2)" ::: "memory");
      __builtin_amdgcn_s_barrier();
      __builtin_amdgcn_sched_barrier(0);
    }
  }

  const float bvl = bias[bn];
#pragma unroll
  for (int m = 0; m < 8; ++m)
#pragma unroll
    for (int r = 0; r < 4; ++r) {
      float v = acc[m][r] + bvl;
      if (do_tanh) v = tanhf(v);
      Out[(size_t)(m * 16 + a_kq * 4 + r) * HH + bn] = f2bf(v);
    }
}

// grid 24: z = bid/12 picks head (0: cls-dense->H1b, 1: con-dense->H2b)
__global__ __launch_bounds__(256) void heads_mfma(
    const unsigned short* __restrict__ pooledb,
    const unsigned short* __restrict__ Wt0, const float* __restrict__ b0,
    unsigned short* __restrict__ H1b,
    const unsigned short* __restrict__ Wt1, const float* __restrict__ b1,
    unsigned short* __restrict__ H2b) {
  __shared__ unsigned short Abuf[3][128 * 64];
  const int z = blockIdx.x / 12;
  const int q0 = (blockIdx.x % 12) * 64;
  head_core(Abuf, pooledb, z ? Wt1 : Wt0, z ? b1 : b0, z ? H2b : H1b, true, q0,
            threadIdx.x);
}

// grid 140: bid<12 -> Yb = H2b @ Wt2^T + b (no act); bid>=12 -> cls CE row.
__global__ __launch_bounds__(256) void out_cls(
    const unsigned short* __restrict__ H2b, const unsigned short* __restrict__ Wt2,
    const float* __restrict__ b2v, unsigned short* __restrict__ Yb,
    const unsigned short* __restrict__ H1b, const float* __restrict__ W2,
    const float* __restrict__ cb2, const int* __restrict__ labels,
    float* __restrict__ out) {
  __shared__ unsigned short Abuf[3][128 * 64];
  const int tid = threadIdx.x;
  if (blockIdx.x < 12) {
    head_core(Abuf, H2b, Wt2, b2v, Yb, false, blockIdx.x * 64, tid);
  } else {
    __shared__ float sh0[4], sh1[4];
    const int b = blockIdx.x - 12;
    const int lane = tid & 63, wid = tid >> 6;
    float p0 = 0.f, p1 = 0.f;
    for (int h = tid; h < HH; h += 256) {
      const float v = bf2f(H1b[(size_t)b * HH + h]);
      p0 = fmaf(v, W2[h * 2 + 0], p0);
      p1 = fmaf(v, W2[h * 2 + 1], p1);
    }
    for (int o = 32; o; o >>= 1) {
      p0 += __shfl_down(p0, o);
      p1 += __shfl_down(p1, o);
    }
    if (lane == 0) { sh0[wid] = p0; sh1[wid] = p1; }
    __syncthreads();
    if (tid == 0) {
      const float l0 = sh0[0] + sh0[1] + sh0[2] + sh0[3] + cb2[0];
      const float l1 = sh1[0] + sh1[1] + sh1[2] + sh1[3] + cb2[1];
      const float mx = fmaxf(l0, l1), mn = fminf(l0, l1);
      const float lse = mx + log1pf(__expf(mn - mx));
      const float ce = lse - (labels[b] ? l1 : l0);
      atomicAdd(out, 0.9f * ce * (1.0f / 128.0f));
    }
  }
}

// cos GEMM v17: 8 waves (512 thr), BM=128 x BN=64, grid=512 -> 4 waves/SIMD.
// Wave w: col-group g=w>>1 (16 cols), m-half h=w&1 (64 rows). Quad-buffered
// gl16 A-staging (2 gl16/wave/chunk), per-wave counted-vmcnt, bf16 C out.
__global__ __launch_bounds__(512, 4) void cos_gemm_mfma(
    const unsigned short* __restrict__ qh, const float* __restrict__ FQ,
    unsigned short* __restrict__ Cb) {
  __shared__ unsigned short Abuf[4][128 * 64];  // 4 x 16 KB
  const int tid = threadIdx.x;
  const int lane = tid & 63, wid = tid >> 6;  // 8 waves
  const int bid = blockIdx.x;
  const int swz = (bid & 7) * 64 + (bid >> 3);  // bijective XCD swizzle
  const int q0 = swz * 64;
  const int a_r = lane & 15, a_kq = lane >> 4;
  const int g = wid >> 1, h = wid & 1;

  // A staging: wave w stages rows [w*16, w*16+16) per chunk via 2 gl16.
  int asrc[2], adst[2];
#pragma unroll
  for (int j = 0; j < 2; ++j) {
    const int rr = wid * 16 + j * 8 + (lane >> 3);
    const int kb = (lane & 7) ^ (rr & 7);
    asrc[j] = rr * HH + kb * 8;
    adst[j] = (wid * 16 + j * 8) * 64;
  }
  // B: fq row = q0 + g*16 + a_r; k = s*32 + a_kq*8
  const float* __restrict__ bptr = FQ + (size_t)(q0 + g * 16 + a_r) * HH + a_kq * 8;
  int aslot[2];
#pragma unroll
  for (int st = 0; st < 2; ++st) aslot[st] = (((st * 4 + a_kq) ^ (a_r & 7)) << 3);

  f32x4 acc[4];
#pragma unroll
  for (int m = 0; m < 4; ++m) acc[m] = (f32x4){0.f, 0.f, 0.f, 0.f};

  // prologue: G0 | G1 | G2 | B s=0..3 (8 loads) | vmcnt(12) -> buf0 ready
#pragma unroll
  for (int j = 0; j < 2; ++j) gl16(qh + asrc[j], &Abuf[0][adst[j]]);
  __builtin_amdgcn_sched_barrier(0);
#pragma unroll
  for (int j = 0; j < 2; ++j) gl16(qh + 64 + asrc[j], &Abuf[1][adst[j]]);
  __builtin_amdgcn_sched_barrier(0);
#pragma unroll
  for (int j = 0; j < 2; ++j) gl16(qh + 128 + asrc[j], &Abuf[2][adst[j]]);
  __builtin_amdgcn_sched_barrier(0);
  float4 bv[4][2];
#pragma unroll
  for (int p = 0; p < 4; ++p) {
    bv[p][0] = *reinterpret_cast<const float4*>(bptr + p * 32);
    bv[p][1] = *reinterpret_cast<const float4*>(bptr + p * 32 + 4);
  }
  __builtin_amdgcn_sched_barrier(0);
  asm volatile("s_waitcnt vmcnt(12)" ::: "memory");  // G0(2) retired
  __builtin_amdgcn_s_barrier();
  __builtin_amdgcn_sched_barrier(0);

#pragma unroll
  for (int c = 0; c < 12; ++c) {
    if (c + 3 < 12) {
#pragma unroll
      for (int j = 0; j < 2; ++j)
        gl16(qh + (c + 3) * 64 + asrc[j], &Abuf[(c + 3) & 3][adst[j]]);
    }
    __builtin_amdgcn_sched_barrier(0);  // pin gl16 batch above B/MFMA region
    const unsigned short* __restrict__ Ab = Abuf[c & 3];
#pragma unroll
    for (int st = 0; st < 2; ++st) {
      const int s = c * 2 + st;
      const float4 v0 = bv[s & 3][0], v1 = bv[s & 3][1];
      if (s + 4 < 24) {
        bv[s & 3][0] = *reinterpret_cast<const float4*>(bptr + (s + 4) * 32);
        bv[s & 3][1] = *reinterpret_cast<const float4*>(bptr + (s + 4) * 32 + 4);
      }
      union { short8 s8; unsigned u[4]; } cbu;
      cbu.u[0] = cvtpk(v0.x, v0.y);
      cbu.u[1] = cvtpk(v0.z, v0.w);
      cbu.u[2] = cvtpk(v1.x, v1.y);
      cbu.u[3] = cvtpk(v1.z, v1.w);
      const short8 bb = cbu.s8;
      const int sl = aslot[st];
#pragma unroll
      for (int m = 0; m < 4; ++m) {
        const short8 aa = *reinterpret_cast<const short8*>(
            &Ab[(h * 64 + m * 16 + a_r) * 64 + sl]);
        acc[m] = __builtin_amdgcn_mfma_f32_16x16x32_bf16(aa, bb, acc[m], 0, 0, 0);
      }
    }
    if (c < 11) {
      __builtin_amdgcn_sched_barrier(0);  // pin B/MFMA region above the wait
      // Per-wave ladder (2 G + 4 B per chunk, pinned order). Need G(c+1)(2):
      //  c==0 (G1 in prologue): G2(2)+Bpro(8)+G3(2)+Bc0(4) = 16
      //  c==1 (G2 in prologue): Bpro(8)+G3(2)+Bc0(4)+G4(2)+Bc1(4) = 20
      //  2<=c<=8: B(c-2)(4)+G(c+2)(2)+B(c-1)(4)+G(c+3)(2)+B(c)(4) = 16
      //           (at c==8: G10,G11 still issued; Bc8 at s=16,17 < 20 ok)
      //  c==9 (need G10, issued c=7): Bc7(4)+G11(2)+Bc8(4)+Bc9(4) = 14
      //  c==10 (need G11, issued c=8): Bc8(4)+Bc9(4) = 8
      if (c == 0)      asm volatile("s_waitcnt vmcnt(16)" ::: "memory");
      else if (c == 1) asm volatile("s_waitcnt vmcnt(20)" ::: "memory");
      else if (c <= 8) asm volatile("s_waitcnt vmcnt(16)" ::: "memory");
      else if (c == 9) asm volatile("s_waitcnt vmcnt(14)" ::: "memory");
      else             asm volatile("s_waitcnt vmcnt(8)" ::: "memory");
      __builtin_amdgcn_s_barrier();
      __builtin_amdgcn_sched_barrier(0);
    }
  }

  const int ccol = q0 + g * 16 + a_r;
#pragma unroll
  for (int m = 0; m < 4; ++m)
#pragma unroll
    for (int r = 0; r < 4; ++r)
      Cb[(size_t)(h * 64 + m * 16 + a_kq * 4 + r) * KQ + ccol] = f2bf(acc[m][r]);
}

// Self-contained select; reads bf16 C rows.
__global__ __launch_bounds__(1024) void select_kernel(
    const unsigned short* __restrict__ Cb, const unsigned short* __restrict__ Yb,
    const int* __restrict__ labels, const int* __restrict__ lq,
    float* __restrict__ out) {
  const int b = blockIdx.x;
  const int tid = threadIdx.x;
  const int lane = tid & 63, wid = tid >> 6;
  const unsigned short* __restrict__ row = Cb + (size_t)b * KQ;
  const int lab = labels[b];

  __shared__ __align__(16) unsigned poskeys[PCAP];
  __shared__ unsigned hist[NB + 1];
  __shared__ unsigned cand[3][CCAP];
  __shared__ int candn[3];
  __shared__ float redm[16], reds[16], redmin[16], redmax[16];
  __shared__ int redn[16];
  __shared__ unsigned wsum[16];
  __shared__ int abin[3], acnt[3];
  __shared__ unsigned akey[3];
  __shared__ unsigned long long accg;
  __shared__ float gs0, gsm, s_logE, s_vmin, s_vmax, s_rs;
  __shared__ float ssq[2];
  __shared__ int s_cnt, s_m, has01;

  if (tid == 0) { s_cnt = 0; gs0 = 0.f; gsm = 0.f; accg = 0ull; has01 = 0; }
  if (tid < 3) candn[tid] = 0;

  float ssl = 0.f;
  if (tid < 96) {
    const short8 y8 =
        *reinterpret_cast<const short8*>(Yb + (size_t)b * HH + tid * 8);
#pragma unroll
    for (int e = 0; e < 8; ++e) {
      const float v = bf2f((unsigned short)y8[e]);
      ssl = fmaf(v, v, ssl);
    }
  }
#pragma unroll
  for (int o = 32; o; o >>= 1) ssl += __shfl_down(ssl, o);
  if (lane == 0 && wid < 2) ssq[wid] = ssl;
  __syncthreads();
  if (tid == 0) s_rs = rsqrtf(ssq[0] + ssq[1]);
  __syncthreads();
  const float rs = s_rs;

  const int base = tid << 5;
  unsigned qm = 0u;
  {
    const int4* __restrict__ lq4 = reinterpret_cast<const int4*>(lq + base);
#pragma unroll
    for (int u = 0; u < 8; ++u) {
      const int4 q = lq4[u];
      qm |= (unsigned)(q.x != 0) << (u * 4 + 0);
      qm |= (unsigned)(q.y != 0) << (u * 4 + 1);
      qm |= (unsigned)(q.z != 0) << (u * 4 + 2);
      qm |= (unsigned)(q.w != 0) << (u * 4 + 3);
    }
  }
  if (tid < BB) atomicOr(&has01, 1 << labels[tid]);
  const unsigned pmask = lab ? qm : ~qm;
  float va[32];
#pragma unroll
  for (int u = 0; u < 4; ++u) {
    const short8 y8 = *reinterpret_cast<const short8*>(row + base + (u << 3));
#pragma unroll
    for (int e = 0; e < 8; ++e)
      va[(u << 3) + e] = bf2f((unsigned short)y8[e]) * rs;
  }
  float mneg = -3.0e38f, sneg = 0.f, vmin = 3.0e38f, vmax = -3.0e38f;
#pragma unroll
  for (int j = 0; j < 32; ++j) {
    if ((pmask >> j) & 1u) {
      vmin = fminf(vmin, va[j]);
      vmax = fmaxf(vmax, va[j]);
    } else {
      mneg = fmaxf(mneg, va[j] * TINV);
    }
  }
#pragma unroll
  for (int j = 0; j < 32; ++j) {
    if (!((pmask >> j) & 1u)) sneg += __expf(va[j] * TINV - mneg);
  }
  int nc = __popc(qm);
#pragma unroll
  for (int o = 32; o; o >>= 1) {
    const float mo = __shfl_down(mneg, o), so = __shfl_down(sneg, o);
    const float M = fmaxf(mneg, mo);
    sneg = sneg * __expf(mneg - M) + so * __expf(mo - M);
    mneg = M;
    vmin = fminf(vmin, __shfl_down(vmin, o));
    vmax = fmaxf(vmax, __shfl_down(vmax, o));
    nc += __shfl_down(nc, o);
  }
  if (lane == 0) {
    redm[wid] = mneg; reds[wid] = sneg; redmin[wid] = vmin; redmax[wid] = vmax;
    redn[wid] = nc;
  }

  const int np = __popc(pmask);
  unsigned incl = (unsigned)np;
#pragma unroll
  for (int o = 1; o < 64; o <<= 1) {
    const unsigned t = __shfl_up(incl, o);
    if (lane >= o) incl += t;
  }
  const unsigned excl = incl - (unsigned)np;
  const unsigned wtot = __shfl(incl, 63);
  unsigned wbase = 0u;
  if (lane == 63) wbase = (unsigned)atomicAdd(&s_cnt, (int)wtot);
  wbase = __shfl(wbase, 63);
  const int ofs = (int)(wbase + excl);
  if (ofs + np <= PCAP) {
#pragma unroll
    for (int j = 0; j < 32; ++j) {
      if ((pmask >> j) & 1u)
        poskeys[ofs + __popc(pmask & ((1u << j) - 1u))] = f2key(va[j]);
    }
  }
  __syncthreads();

  const int P = s_cnt;
  if (tid == 0) {
    float M = redm[0], S = 0.f;
    float mn = redmin[0], mx = redmax[0];
    int n1 = 0;
    for (int w = 1; w < 16; ++w) {
      M = fmaxf(M, redm[w]);
      mn = fminf(mn, redmin[w]);
      mx = fmaxf(mx, redmax[w]);
    }
    for (int w = 0; w < 16; ++w) { S += reds[w] * __expf(redm[w] - M); n1 += redn[w]; }
    s_logE = M + logf(S);
    s_vmin = mn;
    s_vmax = mx;
    int mm = 0x7fffffff;
    if (has01 & 1) mm = min(mm, KQ - n1);
    if (has01 & 2) mm = min(mm, n1);
    s_m = mm;
  }
  if (tid < ((4 - (P & 3)) & 3)) poskeys[P + tid] = 0u;
  for (int i = tid; i < NB + 1; i += 1024) hist[i] = 0u;
  __syncthreads();

  const float cE = s_logE;
  const int m = s_m;
  const float vmn = s_vmin;
  const float scale = (float)NB * (1.0f - 1e-6f) / fmaxf(s_vmax - vmn, 1e-30f);
  auto key2bin = [&](unsigned k) {
    int bn = (int)((key2f(k) - vmn) * scale);
    return bn < 0 ? 0 : (bn > NB - 1 ? NB - 1 : bn);
  };

  for (int i = tid; i < P; i += 1024) atomicAdd(&hist[key2bin(poskeys[i])], 1u);
  __syncthreads();

  const int t4 = tid << 2;
  const unsigned h0 = hist[t4], h1 = hist[t4 + 1], h2 = hist[t4 + 2], h3 = hist[t4 + 3];
  const unsigned part = h0 + h1 + h2 + h3;
  unsigned sinc = part;
#pragma unroll
  for (int o = 1; o < 64; o <<= 1) {
    const unsigned t = __shfl_up(sinc, o);
    if (lane >= o) sinc += t;
  }
  if (lane == 63) wsum[wid] = sinc;
  __syncthreads();
  unsigned woff = 0;
  for (int w = 0; w < wid; ++w) woff += wsum[w];
  const unsigned exb = woff + sinc - part;
  hist[t4] = exb; hist[t4 + 1] = exb + h0; hist[t4 + 2] = exb + h0 + h1;
  hist[t4 + 3] = exb + h0 + h1 + h2;
  if (tid == 1023) hist[NB] = exb + part;
  __syncthreads();

  const int rt0 = 25, rt1 = m - 25, rt2 = m;
  const unsigned idx0 = (unsigned)(P - rt0), idx1 = (unsigned)(P - rt1), idx2 = (unsigned)(P - rt2);
#pragma unroll
  for (int i = 0; i < 4; ++i) {
    const int bb = t4 + i;
    const unsigned pb = hist[bb], pb1 = hist[bb + 1];
    if (pb <= idx0 && idx0 < pb1) { abin[0] = bb; acnt[0] = P - (int)pb1; }
    if (pb <= idx1 && idx1 < pb1) { abin[1] = bb; acnt[1] = P - (int)pb1; }
    if (pb <= idx2 && idx2 < pb1) { abin[2] = bb; acnt[2] = P - (int)pb1; }
  }
  __syncthreads();

  const int tb0 = abin[0], tb1 = abin[1], tb2 = abin[2];
  for (int i = tid; i < P; i += 1024) {
    const unsigned k = poskeys[i];
    const int bn = key2bin(k);
    if (bn == tb0) { const int p = atomicAdd(&candn[0], 1); if (p < CCAP) cand[0][p] = k; }
    if (bn == tb1) { const int p = atomicAdd(&candn[1], 1); if (p < CCAP) cand[1][p] = k; }
    if (bn == tb2) { const int p = atomicAdd(&candn[2], 1); if (p < CCAP) cand[2][p] = k; }
  }
  __syncthreads();

  if (wid < 3) {
    const int j = wid;
    const int rts[3] = {rt0, rt1, rt2};
    const int cnt = candn[j] < CCAP ? candn[j] : CCAP;
    const int rr = rts[j] - acnt[j];
    for (int i = lane; i < cnt; i += 64) {
      const unsigned k = cand[j][i];
      int gt = 0, eq = 0;
      for (int q = 0; q < cnt; ++q) {
        const unsigned kq = cand[j][q];
        gt += (kq > k);
        eq += (kq == k);
      }
      if (gt < rr && rr <= gt + eq) akey[j] = k;
    }
  }
  __syncthreads();

  const unsigned a0 = akey[0], a1 = akey[1], a2 = akey[2];
  const int P4c = (P + 3) >> 2;
  const uint4* __restrict__ pk4 = reinterpret_cast<const uint4*>(poskeys);

  float s0 = 0.f, sm = 0.f;
  unsigned q0c = 0, q1c = 0, q2c = 0;
  for (int i = tid; i < P4c; i += 1024) {
    const uint4 kv = pk4[i];
    const unsigned ks[4] = {kv.x, kv.y, kv.z, kv.w};
#pragma unroll
    for (int j = 0; j < 4; ++j) {
      const unsigned k = ks[j];
      if (k > a2) {
        ++q2c;
        const bool top = (k > a0), mid = (k <= a1);
        if (k > a1) ++q1c;
        if (top) ++q0c;
        if (top || mid) {
          const float a = key2f(k) * TINV;
          const float d = cE - a;
          const float fv = fmaxf(d, 0.f) + log1pf(__expf(-fabsf(d)));
          if (top) s0 += fv;
          if (mid) sm += fv;
        }
      }
    }
  }
  unsigned long long pc = (unsigned long long)q0c |
                          ((unsigned long long)q1c << 20) |
                          ((unsigned long long)q2c << 40);
#pragma unroll
  for (int o = 32; o; o >>= 1) {
    s0 += __shfl_down(s0, o);
    sm += __shfl_down(sm, o);
    pc += shfl_down_u64(pc, o);
  }
  if (lane == 0) {
    atomicAdd(&gs0, s0);
    atomicAdd(&gsm, sm);
    atomicAdd(&accg, pc);
  }
  __syncthreads();
  if (tid == 0) {
    const unsigned long long t = accg;
    const float C0 = (float)(unsigned)(t & 0xFFFFFu);
    const float C1 = (float)(unsigned)((t >> 20) & 0xFFFFFu);
    const float C2 = (float)(unsigned)((t >> 40) & 0xFFFFFu);
    auto fval = [&](unsigned kk) {
      const float a = key2f(kk) * TINV;
      const float d = cE - a;
      return fmaxf(d, 0.f) + log1pf(__expf(-fabsf(d)));
    };
    const float f0 = fval(a0), f1 = fval(a1), f2 = fval(a2);
    const float top25 = gs0 + (25.0f - C0) * f0;
    const float mid = gsm + ((float)m - C2) * f2 - ((float)(m - 25) - C1) * f1;
    atomicAdd(out, 0.1f * (top25 + mid) * (1.0f / 6400.0f));
  }
}

extern "C" void kernel_launch(void* const* d_in, const int* in_sizes, int n_in,
                              void* d_out, int out_size, void* d_ws, size_t ws_size,
                              hipStream_t stream) {
  const float* pooled = (const float*)d_in[0];
  const int* labels = (const int*)d_in[1];
  const float* fq = (const float*)d_in[2];
  const int* lq = (const int*)d_in[3];
  const float* cls_dw = (const float*)d_in[4];
  const float* cls_db = (const float*)d_in[5];
  const float* cls_ow = (const float*)d_in[6];
  const float* cls_ob = (const float*)d_in[7];
  const float* con_dw = (const float*)d_in[8];
  const float* con_db = (const float*)d_in[9];
  const float* con_ow = (const float*)d_in[10];
  const float* con_ob = (const float*)d_in[11];
  float* out = (float*)d_out;

  // Layout: [Cb: 8MB bf16][Yb|H1b|H2b|pooledb: 4x192KB]. Wt0..2 (bf16 768^2
  // each, 3.4MB total) alias the FRONT of Cb — dead before cos writes Cb.
  float* ws = (float*)d_ws;
  unsigned short* Cb = (unsigned short*)ws;                 // 128*32768 bf16
  unsigned short* Yb = Cb + (size_t)BB * KQ;
  unsigned short* H1b = Yb + 98304;
  unsigned short* H2b = H1b + 98304;
  unsigned short* pooledb = H2b + 98304;
  unsigned short* Wt0 = Cb;                                 // aliases Cb
  unsigned short* Wt1 = Wt0 + 589824;
  unsigned short* Wt2 = Wt1 + 589824;

  prep_kernel<<<528, 256, 0, stream>>>(cls_dw, con_dw, con_ow, pooled,
                                       Wt0, Wt1, Wt2, pooledb, out);
  heads_mfma<<<24, 256, 0, stream>>>(pooledb, Wt0, cls_db, H1b,
                                     Wt1, con_db, H2b);
  out_cls<<<140, 256, 0, stream>>>(H2b, Wt2, con_ob, Yb,
                                   H1b, cls_ow, cls_ob, labels, out);
  cos_gemm_mfma<<<512, 512, 0, stream>>>(Yb, fq, Cb);
  select_kernel<<<128, 1024, 0, stream>>>(Cb, Yb, labels, lq, out);
}

// Round 18
// 81.568 us; speedup vs baseline: 1.0990x; 1.0990x over previous
//
#include <hip/hip_runtime.h>
#include <math.h>

#define BB 128
#define HH 768
#define KQ 32768
#define PCAP 18432  // max positives per row staged in LDS
#define NB 4096     // histogram bins
#define CCAP 512    // candidate cap per target bin

constexpr float TINV = 1.0f / 0.07f;

typedef __attribute__((ext_vector_type(8))) short short8;
typedef __attribute__((ext_vector_type(4))) float f32x4;
typedef __attribute__((address_space(3))) void lds_void;
typedef const __attribute__((address_space(1))) void gbl_void;

__device__ __forceinline__ unsigned short f2bf(float f) {
  unsigned u = __float_as_uint(f);
  unsigned r = u + 0x7FFFu + ((u >> 16) & 1u);  // RNE
  return (unsigned short)(r >> 16);
}
__device__ __forceinline__ float bf2f(unsigned short h) {
  return __uint_as_float(((unsigned)h) << 16);
}
__device__ __forceinline__ unsigned cvtpk(float a, float b) {
  unsigned r;
  asm("v_cvt_pk_bf16_f32 %0, %1, %2" : "=v"(r) : "v"(a), "v"(b));
  return r;
}
__device__ __forceinline__ unsigned f2key(float f) {
  unsigned u = __float_as_uint(f);
  return u ^ (unsigned)(((int)u >> 31) | 0x80000000);
}
__device__ __forceinline__ float key2f(unsigned k) {
  unsigned u = (k & 0x80000000u) ? (k & 0x7FFFFFFFu) : ~k;
  return __uint_as_float(u);
}
__device__ __forceinline__ unsigned long long shfl_down_u64(unsigned long long v, int o) {
  unsigned lo = (unsigned)v, hi = (unsigned)(v >> 32);
  lo = __shfl_down(lo, o);
  hi = __shfl_down(hi, o);
  return ((unsigned long long)hi << 32) | lo;
}
__device__ __forceinline__ void gl16(const unsigned short* g, unsigned short* l) {
  __builtin_amdgcn_global_load_lds((gbl_void*)g, (lds_void*)l, 16, 0, 0);
}

// prep: bid<432 -> transpose W{0,1,2} (768x768 f32) into Wt (bf16, [n][k]);
//       bid>=432 -> pooled f32 -> bf16. Block 0 zeroes out[0].
__global__ __launch_bounds__(256) void prep_kernel(
    const float* __restrict__ W0, const float* __restrict__ W1,
    const float* __restrict__ W2, const float* __restrict__ pooled,
    unsigned short* __restrict__ Wt0, unsigned short* __restrict__ Wt1,
    unsigned short* __restrict__ Wt2, unsigned short* __restrict__ pooledb,
    float* __restrict__ out) {
  const int bid = blockIdx.x, tid = threadIdx.x;
  if (bid == 0 && tid == 0) out[0] = 0.0f;
  if (bid < 432) {
    const float* W = (bid < 144) ? W0 : (bid < 288 ? W1 : W2);
    unsigned short* Wt = (bid < 144) ? Wt0 : (bid < 288 ? Wt1 : Wt2);
    const int t = bid % 144;
    const int k0 = (t / 12) * 64, n0 = (t % 12) * 64;
    __shared__ float Ls[64][65];
    const int r = tid >> 4, c4 = (tid & 15) * 4;
#pragma unroll
    for (int i = 0; i < 4; ++i) {
      const int rr = r + i * 16;
      const float4 v = *reinterpret_cast<const float4*>(W + (size_t)(k0 + rr) * HH + n0 + c4);
      Ls[rr][c4 + 0] = v.x; Ls[rr][c4 + 1] = v.y;
      Ls[rr][c4 + 2] = v.z; Ls[rr][c4 + 3] = v.w;
    }
    __syncthreads();
#pragma unroll
    for (int i = 0; i < 4; ++i) {
      const int rn = r + i * 16;  // n-local
      ushort4 o;
      o.x = f2bf(Ls[c4 + 0][rn]);
      o.y = f2bf(Ls[c4 + 1][rn]);
      o.z = f2bf(Ls[c4 + 2][rn]);
      o.w = f2bf(Ls[c4 + 3][rn]);
      *reinterpret_cast<ushort4*>(Wt + (size_t)(n0 + rn) * HH + k0 + c4) = o;
    }
  } else {
    const int idx = (bid - 432) * 1024 + tid * 4;
    const float4 v = *reinterpret_cast<const float4*>(pooled + idx);
    ushort4 o;
    o.x = f2bf(v.x); o.y = f2bf(v.y); o.z = f2bf(v.z); o.w = f2bf(v.w);
    *reinterpret_cast<ushort4*>(pooledb + idx) = o;
  }
}

// MFMA head GEMM core: Out[128,768](bf16) cols [q0,q0+64) =
//   act(Ab[128,768](bf16) @ Wt^T + bias). Tri-buffered gl16 A-staging,
//   counted-vmcnt, B = direct 16B bf16 loads (1/step).
__device__ __forceinline__ void head_core(
    unsigned short (*Abuf)[128 * 64], const unsigned short* __restrict__ Ab,
    const unsigned short* __restrict__ Wt, const float* __restrict__ bias,
    unsigned short* __restrict__ Out, bool do_tanh, int q0, int tid) {
  const int lane = tid & 63, wid = tid >> 6;
  const int a_r = lane & 15, a_kq = lane >> 4;
  int asrc[4], adst[4];
#pragma unroll
  for (int j = 0; j < 4; ++j) {
    const int rr = (wid * 4 + j) * 8 + (lane >> 3);
    const int kb = (lane & 7) ^ (rr & 7);
    asrc[j] = rr * HH + kb * 8;
    adst[j] = (wid * 4 + j) * 512;
  }
  const int bn = q0 + wid * 16 + a_r;
  const unsigned short* __restrict__ bptr = Wt + (size_t)bn * HH + a_kq * 8;
  int aslot[2];
#pragma unroll
  for (int st = 0; st < 2; ++st) aslot[st] = (((st * 4 + a_kq) ^ (a_r & 7)) << 3);

  f32x4 acc[8];
#pragma unroll
  for (int m = 0; m < 8; ++m) acc[m] = (f32x4){0.f, 0.f, 0.f, 0.f};

#pragma unroll
  for (int j = 0; j < 4; ++j) gl16(Ab + asrc[j], &Abuf[0][adst[j]]);
  __builtin_amdgcn_sched_barrier(0);
#pragma unroll
  for (int j = 0; j < 4; ++j) gl16(Ab + 64 + asrc[j], &Abuf[1][adst[j]]);
  __builtin_amdgcn_sched_barrier(0);
  short8 bv[4];
#pragma unroll
  for (int p = 0; p < 4; ++p)
    bv[p] = *reinterpret_cast<const short8*>(bptr + p * 32);
  __builtin_amdgcn_sched_barrier(0);
  asm volatile("s_waitcnt vmcnt(8)" ::: "memory");  // G0 retired
  __builtin_amdgcn_s_barrier();
  __builtin_amdgcn_sched_barrier(0);

#pragma unroll
  for (int c = 0; c < 12; ++c) {
    if (c + 2 < 12) {
#pragma unroll
      for (int j = 0; j < 4; ++j)
        gl16(Ab + (c + 2) * 64 + asrc[j], &Abuf[(c + 2) % 3][adst[j]]);
    }
    __builtin_amdgcn_sched_barrier(0);
    const unsigned short* __restrict__ Abc = Abuf[c % 3];
#pragma unroll
    for (int st = 0; st < 2; ++st) {
      const int s = c * 2 + st;
      const short8 bb = bv[s & 3];
      if (s + 4 < 24)
        bv[s & 3] = *reinterpret_cast<const short8*>(bptr + (s + 4) * 32);
      const int sl = aslot[st];
#pragma unroll
      for (int m = 0; m < 8; ++m) {
        const short8 aa =
            *reinterpret_cast<const short8*>(&Abc[(m * 16 + a_r) * 64 + sl]);
        acc[m] = __builtin_amdgcn_mfma_f32_16x16x32_bf16(aa, bb, acc[m], 0, 0, 0);
      }
    }
    if (c < 11) {
      __builtin_amdgcn_sched_barrier(0);
      if (c == 0)       asm volatile("s_waitcnt vmcnt(10)" ::: "memory");
      else if (c <= 9)  asm volatile("s_waitcnt vmcnt(8)" ::: "memory");
      else              asm volatile("s_waitcnt vmcnt(2)" ::: "memory");
      __builtin_amdgcn_s_barrier();
      __builtin_amdgcn_sched_barrier(0);
    }
  }

  const float bvl = bias[bn];
#pragma unroll
  for (int m = 0; m < 8; ++m)
#pragma unroll
    for (int r = 0; r < 4; ++r) {
      float v = acc[m][r] + bvl;
      if (do_tanh) v = tanhf(v);
      Out[(size_t)(m * 16 + a_kq * 4 + r) * HH + bn] = f2bf(v);
    }
}

// grid 24: z = bid/12 picks head (0: cls-dense->H1b, 1: con-dense->H2b)
__global__ __launch_bounds__(256) void heads_mfma(
    const unsigned short* __restrict__ pooledb,
    const unsigned short* __restrict__ Wt0, const float* __restrict__ b0,
    unsigned short* __restrict__ H1b,
    const unsigned short* __restrict__ Wt1, const float* __restrict__ b1,
    unsigned short* __restrict__ H2b) {
  __shared__ unsigned short Abuf[3][128 * 64];
  const int z = blockIdx.x / 12;
  const int q0 = (blockIdx.x % 12) * 64;
  head_core(Abuf, pooledb, z ? Wt1 : Wt0, z ? b1 : b0, z ? H2b : H1b, true, q0,
            threadIdx.x);
}

// grid 12: Yb = H2b @ Wt2^T + b (no act). (cls CE moved into select_kernel.)
__global__ __launch_bounds__(256) void out_gemm(
    const unsigned short* __restrict__ H2b, const unsigned short* __restrict__ Wt2,
    const float* __restrict__ b2v, unsigned short* __restrict__ Yb) {
  __shared__ unsigned short Abuf[3][128 * 64];
  head_core(Abuf, H2b, Wt2, b2v, Yb, false, blockIdx.x * 64, threadIdx.x);
}

// cos GEMM v16 (R16, best): 256 thr, quad-buffered counted-vmcnt, bf16 C out.
__global__ __launch_bounds__(256, 2) void cos_gemm_mfma(
    const unsigned short* __restrict__ qh, const float* __restrict__ FQ,
    unsigned short* __restrict__ Cb) {
  __shared__ unsigned short Abuf[4][128 * 64];  // 4 x 16 KB
  const int tid = threadIdx.x;
  const int lane = tid & 63, wid = tid >> 6;
  const int bid = blockIdx.x;
  const int swz = (bid & 7) * 64 + (bid >> 3);
  const int q0 = swz * 64;
  const int a_r = lane & 15, a_kq = lane >> 4;

  int asrc[4], adst[4];
#pragma unroll
  for (int j = 0; j < 4; ++j) {
    const int rr = (wid * 4 + j) * 8 + (lane >> 3);
    const int kb = (lane & 7) ^ (rr & 7);
    asrc[j] = rr * HH + kb * 8;
    adst[j] = (wid * 4 + j) * 512;
  }
  const float* __restrict__ bptr = FQ + (size_t)(q0 + wid * 16 + a_r) * HH + a_kq * 8;
  int aslot[2];
#pragma unroll
  for (int st = 0; st < 2; ++st) aslot[st] = (((st * 4 + a_kq) ^ (a_r & 7)) << 3);

  f32x4 acc[8];
#pragma unroll
  for (int m = 0; m < 8; ++m) acc[m] = (f32x4){0.f, 0.f, 0.f, 0.f};

#pragma unroll
  for (int j = 0; j < 4; ++j) gl16(qh + asrc[j], &Abuf[0][adst[j]]);
  __builtin_amdgcn_sched_barrier(0);
#pragma unroll
  for (int j = 0; j < 4; ++j) gl16(qh + 64 + asrc[j], &Abuf[1][adst[j]]);
  __builtin_amdgcn_sched_barrier(0);
#pragma unroll
  for (int j = 0; j < 4; ++j) gl16(qh + 128 + asrc[j], &Abuf[2][adst[j]]);
  __builtin_amdgcn_sched_barrier(0);
  float4 bv[8][2];
#pragma unroll
  for (int p = 0; p < 8; ++p) {
    bv[p][0] = *reinterpret_cast<const float4*>(bptr + p * 32);
    bv[p][1] = *reinterpret_cast<const float4*>(bptr + p * 32 + 4);
  }
  __builtin_amdgcn_sched_barrier(0);
  asm volatile("s_waitcnt vmcnt(24)" ::: "memory");  // G0 retired
  __builtin_amdgcn_s_barrier();
  __builtin_amdgcn_sched_barrier(0);

#pragma unroll
  for (int c = 0; c < 12; ++c) {
    if (c + 3 < 12) {
#pragma unroll
      for (int j = 0; j < 4; ++j)
        gl16(qh + (c + 3) * 64 + asrc[j], &Abuf[(c + 3) & 3][adst[j]]);
    }
    __builtin_amdgcn_sched_barrier(0);  // pin gl16 batch above B/MFMA region
    const unsigned short* __restrict__ Ab = Abuf[c & 3];
#pragma unroll
    for (int st = 0; st < 2; ++st) {
      const int s = c * 2 + st;
      const float4 v0 = bv[s & 7][0], v1 = bv[s & 7][1];
      if (s + 8 < 24) {
        bv[s & 7][0] = *reinterpret_cast<const float4*>(bptr + (s + 8) * 32);
        bv[s & 7][1] = *reinterpret_cast<const float4*>(bptr + (s + 8) * 32 + 4);
      }
      union { short8 s8; unsigned u[4]; } cb;
      cb.u[0] = cvtpk(v0.x, v0.y);
      cb.u[1] = cvtpk(v0.z, v0.w);
      cb.u[2] = cvtpk(v1.x, v1.y);
      cb.u[3] = cvtpk(v1.z, v1.w);
      const short8 bb = cb.s8;
      const int sl = aslot[st];
#pragma unroll
      for (int m = 0; m < 8; ++m) {
        const short8 aa =
            *reinterpret_cast<const short8*>(&Ab[(m * 16 + a_r) * 64 + sl]);
        acc[m] = __builtin_amdgcn_mfma_f32_16x16x32_bf16(aa, bb, acc[m], 0, 0, 0);
      }
    }
    if (c < 11) {
      __builtin_amdgcn_sched_barrier(0);  // pin B/MFMA region above the wait
      if (c == 0)      asm volatile("s_waitcnt vmcnt(28)" ::: "memory");
      else if (c == 1) asm volatile("s_waitcnt vmcnt(32)" ::: "memory");
      else if (c <= 7) asm volatile("s_waitcnt vmcnt(20)" ::: "memory");
      else if (c == 8) asm volatile("s_waitcnt vmcnt(16)" ::: "memory");
      else if (c == 9) asm volatile("s_waitcnt vmcnt(8)" ::: "memory");
      else             asm volatile("s_waitcnt vmcnt(0)" ::: "memory");
      __builtin_amdgcn_s_barrier();
      __builtin_amdgcn_sched_barrier(0);
    }
  }

  const int ccol = q0 + wid * 16 + a_r;
#pragma unroll
  for (int m = 0; m < 8; ++m)
#pragma unroll
    for (int r = 0; r < 4; ++r)
      Cb[(size_t)(m * 16 + a_kq * 4 + r) * KQ + ccol] = f2bf(acc[m][r]);
}

// Self-contained select (bf16 C rows) + folded cls-CE for row b.
__global__ __launch_bounds__(1024) void select_kernel(
    const unsigned short* __restrict__ Cb, const unsigned short* __restrict__ Yb,
    const unsigned short* __restrict__ H1b, const float* __restrict__ W2,
    const float* __restrict__ cb2, const int* __restrict__ labels,
    const int* __restrict__ lq, float* __restrict__ out) {
  const int b = blockIdx.x;
  const int tid = threadIdx.x;
  const int lane = tid & 63, wid = tid >> 6;
  const unsigned short* __restrict__ row = Cb + (size_t)b * KQ;
  const int lab = labels[b];

  __shared__ __align__(16) unsigned poskeys[PCAP];
  __shared__ unsigned hist[NB + 1];
  __shared__ unsigned cand[3][CCAP];
  __shared__ int candn[3];
  __shared__ float redm[16], reds[16], redmin[16], redmax[16];
  __shared__ int redn[16];
  __shared__ unsigned wsum[16];
  __shared__ float shc0[16], shc1[16];
  __shared__ int abin[3], acnt[3];
  __shared__ unsigned akey[3];
  __shared__ unsigned long long accg;
  __shared__ float gs0, gsm, s_logE, s_vmin, s_vmax, s_rs;
  __shared__ float ssq[2];
  __shared__ int s_cnt, s_m, has01;

  if (tid == 0) { s_cnt = 0; gs0 = 0.f; gsm = 0.f; accg = 0ull; has01 = 0; }
  if (tid < 3) candn[tid] = 0;

  // ---------- folded cls CE partials for row b ----------
  float cp0 = 0.f, cp1 = 0.f;
  if (tid < HH) {
    const float v = bf2f(H1b[(size_t)b * HH + tid]);
    cp0 = v * W2[tid * 2 + 0];
    cp1 = v * W2[tid * 2 + 1];
  }
#pragma unroll
  for (int o = 32; o; o >>= 1) {
    cp0 += __shfl_down(cp0, o);
    cp1 += __shfl_down(cp1, o);
  }
  if (lane == 0) { shc0[wid] = cp0; shc1[wid] = cp1; }

  // ---------- row scale rs = 1/||Yb[b]|| ----------
  float ssl = 0.f;
  if (tid < 96) {
    const short8 y8 =
        *reinterpret_cast<const short8*>(Yb + (size_t)b * HH + tid * 8);
#pragma unroll
    for (int e = 0; e < 8; ++e) {
      const float v = bf2f((unsigned short)y8[e]);
      ssl = fmaf(v, v, ssl);
    }
  }
#pragma unroll
  for (int o = 32; o; o >>= 1) ssl += __shfl_down(ssl, o);
  if (lane == 0 && wid < 2) ssq[wid] = ssl;
  __syncthreads();
  if (tid == 0) s_rs = rsqrtf(ssq[0] + ssq[1]);
  __syncthreads();
  const float rs = s_rs;

  const int base = tid << 5;
  unsigned qm = 0u;
  {
    const int4* __restrict__ lq4 = reinterpret_cast<const int4*>(lq + base);
#pragma unroll
    for (int u = 0; u < 8; ++u) {
      const int4 q = lq4[u];
      qm |= (unsigned)(q.x != 0) << (u * 4 + 0);
      qm |= (unsigned)(q.y != 0) << (u * 4 + 1);
      qm |= (unsigned)(q.z != 0) << (u * 4 + 2);
      qm |= (unsigned)(q.w != 0) << (u * 4 + 3);
    }
  }
  if (tid < BB) atomicOr(&has01, 1 << labels[tid]);
  const unsigned pmask = lab ? qm : ~qm;
  float va[32];
#pragma unroll
  for (int u = 0; u < 4; ++u) {
    const short8 y8 = *reinterpret_cast<const short8*>(row + base + (u << 3));
#pragma unroll
    for (int e = 0; e < 8; ++e)
      va[(u << 3) + e] = bf2f((unsigned short)y8[e]) * rs;
  }
  float mneg = -3.0e38f, sneg = 0.f, vmin = 3.0e38f, vmax = -3.0e38f;
#pragma unroll
  for (int j = 0; j < 32; ++j) {
    if ((pmask >> j) & 1u) {
      vmin = fminf(vmin, va[j]);
      vmax = fmaxf(vmax, va[j]);
    } else {
      mneg = fmaxf(mneg, va[j] * TINV);
    }
  }
#pragma unroll
  for (int j = 0; j < 32; ++j) {
    if (!((pmask >> j) & 1u)) sneg += __expf(va[j] * TINV - mneg);
  }
  int nc = __popc(qm);
#pragma unroll
  for (int o = 32; o; o >>= 1) {
    const float mo = __shfl_down(mneg, o), so = __shfl_down(sneg, o);
    const float M = fmaxf(mneg, mo);
    sneg = sneg * __expf(mneg - M) + so * __expf(mo - M);
    mneg = M;
    vmin = fminf(vmin, __shfl_down(vmin, o));
    vmax = fmaxf(vmax, __shfl_down(vmax, o));
    nc += __shfl_down(nc, o);
  }
  if (lane == 0) {
    redm[wid] = mneg; reds[wid] = sneg; redmin[wid] = vmin; redmax[wid] = vmax;
    redn[wid] = nc;
  }

  const int np = __popc(pmask);
  unsigned incl = (unsigned)np;
#pragma unroll
  for (int o = 1; o < 64; o <<= 1) {
    const unsigned t = __shfl_up(incl, o);
    if (lane >= o) incl += t;
  }
  const unsigned excl = incl - (unsigned)np;
  const unsigned wtot = __shfl(incl, 63);
  unsigned wbase = 0u;
  if (lane == 63) wbase = (unsigned)atomicAdd(&s_cnt, (int)wtot);
  wbase = __shfl(wbase, 63);
  const int ofs = (int)(wbase + excl);
  if (ofs + np <= PCAP) {
#pragma unroll
    for (int j = 0; j < 32; ++j) {
      if ((pmask >> j) & 1u)
        poskeys[ofs + __popc(pmask & ((1u << j) - 1u))] = f2key(va[j]);
    }
  }
  __syncthreads();

  const int P = s_cnt;
  if (tid == 0) {
    float M = redm[0], S = 0.f;
    float mn = redmin[0], mx = redmax[0];
    int n1 = 0;
    for (int w = 1; w < 16; ++w) {
      M = fmaxf(M, redm[w]);
      mn = fminf(mn, redmin[w]);
      mx = fmaxf(mx, redmax[w]);
    }
    for (int w = 0; w < 16; ++w) { S += reds[w] * __expf(redm[w] - M); n1 += redn[w]; }
    s_logE = M + logf(S);
    s_vmin = mn;
    s_vmax = mx;
    int mm = 0x7fffffff;
    if (has01 & 1) mm = min(mm, KQ - n1);
    if (has01 & 2) mm = min(mm, n1);
    s_m = mm;
  }
  if (tid < ((4 - (P & 3)) & 3)) poskeys[P + tid] = 0u;
  for (int i = tid; i < NB + 1; i += 1024) hist[i] = 0u;
  __syncthreads();

  const float cE = s_logE;
  const int m = s_m;
  const float vmn = s_vmin;
  const float scale = (float)NB * (1.0f - 1e-6f) / fmaxf(s_vmax - vmn, 1e-30f);
  auto key2bin = [&](unsigned k) {
    int bn = (int)((key2f(k) - vmn) * scale);
    return bn < 0 ? 0 : (bn > NB - 1 ? NB - 1 : bn);
  };

  for (int i = tid; i < P; i += 1024) atomicAdd(&hist[key2bin(poskeys[i])], 1u);
  __syncthreads();

  const int t4 = tid << 2;
  const unsigned h0 = hist[t4], h1 = hist[t4 + 1], h2 = hist[t4 + 2], h3 = hist[t4 + 3];
  const unsigned part = h0 + h1 + h2 + h3;
  unsigned sinc = part;
#pragma unroll
  for (int o = 1; o < 64; o <<= 1) {
    const unsigned t = __shfl_up(sinc, o);
    if (lane >= o) sinc += t;
  }
  if (lane == 63) wsum[wid] = sinc;
  __syncthreads();
  unsigned woff = 0;
  for (int w = 0; w < wid; ++w) woff += wsum[w];
  const unsigned exb = woff + sinc - part;
  hist[t4] = exb; hist[t4 + 1] = exb + h0; hist[t4 + 2] = exb + h0 + h1;
  hist[t4 + 3] = exb + h0 + h1 + h2;
  if (tid == 1023) hist[NB] = exb + part;
  __syncthreads();

  const int rt0 = 25, rt1 = m - 25, rt2 = m;
  const unsigned idx0 = (unsigned)(P - rt0), idx1 = (unsigned)(P - rt1), idx2 = (unsigned)(P - rt2);
#pragma unroll
  for (int i = 0; i < 4; ++i) {
    const int bb = t4 + i;
    const unsigned pb = hist[bb], pb1 = hist[bb + 1];
    if (pb <= idx0 && idx0 < pb1) { abin[0] = bb; acnt[0] = P - (int)pb1; }
    if (pb <= idx1 && idx1 < pb1) { abin[1] = bb; acnt[1] = P - (int)pb1; }
    if (pb <= idx2 && idx2 < pb1) { abin[2] = bb; acnt[2] = P - (int)pb1; }
  }
  __syncthreads();

  const int tb0 = abin[0], tb1 = abin[1], tb2 = abin[2];
  for (int i = tid; i < P; i += 1024) {
    const unsigned k = poskeys[i];
    const int bn = key2bin(k);
    if (bn == tb0) { const int p = atomicAdd(&candn[0], 1); if (p < CCAP) cand[0][p] = k; }
    if (bn == tb1) { const int p = atomicAdd(&candn[1], 1); if (p < CCAP) cand[1][p] = k; }
    if (bn == tb2) { const int p = atomicAdd(&candn[2], 1); if (p < CCAP) cand[2][p] = k; }
  }
  __syncthreads();

  if (wid < 3) {
    const int j = wid;
    const int rts[3] = {rt0, rt1, rt2};
    const int cnt = candn[j] < CCAP ? candn[j] : CCAP;
    const int rr = rts[j] - acnt[j];
    for (int i = lane; i < cnt; i += 64) {
      const unsigned k = cand[j][i];
      int gt = 0, eq = 0;
      for (int q = 0; q < cnt; ++q) {
        const unsigned kq = cand[j][q];
        gt += (kq > k);
        eq += (kq == k);
      }
      if (gt < rr && rr <= gt + eq) akey[j] = k;
    }
  }
  __syncthreads();

  const unsigned a0 = akey[0], a1 = akey[1], a2 = akey[2];
  const int P4c = (P + 3) >> 2;
  const uint4* __restrict__ pk4 = reinterpret_cast<const uint4*>(poskeys);

  float s0 = 0.f, sm = 0.f;
  unsigned q0c = 0, q1c = 0, q2c = 0;
  for (int i = tid; i < P4c; i += 1024) {
    const uint4 kv = pk4[i];
    const unsigned ks[4] = {kv.x, kv.y, kv.z, kv.w};
#pragma unroll
    for (int j = 0; j < 4; ++j) {
      const unsigned k = ks[j];
      if (k > a2) {
        ++q2c;
        const bool top = (k > a0), mid = (k <= a1);
        if (k > a1) ++q1c;
        if (top) ++q0c;
        if (top || mid) {
          const float a = key2f(k) * TINV;
          const float d = cE - a;
          const float fv = fmaxf(d, 0.f) + log1pf(__expf(-fabsf(d)));
          if (top) s0 += fv;
          if (mid) sm += fv;
        }
      }
    }
  }
  unsigned long long pc = (unsigned long long)q0c |
                          ((unsigned long long)q1c << 20) |
                          ((unsigned long long)q2c << 40);
#pragma unroll
  for (int o = 32; o; o >>= 1) {
    s0 += __shfl_down(s0, o);
    sm += __shfl_down(sm, o);
    pc += shfl_down_u64(pc, o);
  }
  if (lane == 0) {
    atomicAdd(&gs0, s0);
    atomicAdd(&gsm, sm);
    atomicAdd(&accg, pc);
  }
  __syncthreads();
  if (tid == 0) {
    const unsigned long long t = accg;
    const float C0 = (float)(unsigned)(t & 0xFFFFFu);
    const float C1 = (float)(unsigned)((t >> 20) & 0xFFFFFu);
    const float C2 = (float)(unsigned)((t >> 40) & 0xFFFFFu);
    auto fval = [&](unsigned kk) {
      const float a = key2f(kk) * TINV;
      const float d = cE - a;
      return fmaxf(d, 0.f) + log1pf(__expf(-fabsf(d)));
    };
    const float f0 = fval(a0), f1 = fval(a1), f2 = fval(a2);
    const float top25 = gs0 + (25.0f - C0) * f0;
    const float mid = gsm + ((float)m - C2) * f2 - ((float)(m - 25) - C1) * f1;
    // folded cls CE for row b
    float l0 = cb2[0], l1 = cb2[1];
    for (int w = 0; w < 16; ++w) { l0 += shc0[w]; l1 += shc1[w]; }
    const float mx = fmaxf(l0, l1), mn = fminf(l0, l1);
    const float lse = mx + log1pf(__expf(mn - mx));
    const float ce = lse - (lab ? l1 : l0);
    atomicAdd(out, 0.9f * ce * (1.0f / 128.0f) +
                       0.1f * (top25 + mid) * (1.0f / 6400.0f));
  }
}

extern "C" void kernel_launch(void* const* d_in, const int* in_sizes, int n_in,
                              void* d_out, int out_size, void* d_ws, size_t ws_size,
                              hipStream_t stream) {
  const float* pooled = (const float*)d_in[0];
  const int* labels = (const int*)d_in[1];
  const float* fq = (const float*)d_in[2];
  const int* lq = (const int*)d_in[3];
  const float* cls_dw = (const float*)d_in[4];
  const float* cls_db = (const float*)d_in[5];
  const float* cls_ow = (const float*)d_in[6];
  const float* cls_ob = (const float*)d_in[7];
  const float* con_dw = (const float*)d_in[8];
  const float* con_db = (const float*)d_in[9];
  const float* con_ow = (const float*)d_in[10];
  const float* con_ob = (const float*)d_in[11];
  float* out = (float*)d_out;

  // Layout: [Cb: 8MB bf16][Yb|H1b|H2b|pooledb: 4x192KB]. Wt0..2 (bf16 768^2
  // each, 3.4MB total) alias the FRONT of Cb — dead before cos writes Cb.
  float* ws = (float*)d_ws;
  unsigned short* Cb = (unsigned short*)ws;                 // 128*32768 bf16
  unsigned short* Yb = Cb + (size_t)BB * KQ;
  unsigned short* H1b = Yb + 98304;
  unsigned short* H2b = H1b + 98304;
  unsigned short* pooledb = H2b + 98304;
  unsigned short* Wt0 = Cb;                                 // aliases Cb
  unsigned short* Wt1 = Wt0 + 589824;
  unsigned short* Wt2 = Wt1 + 589824;

  prep_kernel<<<528, 256, 0, stream>>>(cls_dw, con_dw, con_ow, pooled,
                                       Wt0, Wt1, Wt2, pooledb, out);
  heads_mfma<<<24, 256, 0, stream>>>(pooledb, Wt0, cls_db, H1b,
                                     Wt1, con_db, H2b);
  out_gemm<<<12, 256, 0, stream>>>(H2b, Wt2, con_ob, Yb);
  cos_gemm_mfma<<<512, 256, 0, stream>>>(Yb, fq, Cb);
  select_kernel<<<128, 1024, 0, stream>>>(Cb, Yb, H1b, cls_ow, cls_ob,
                                          labels, lq, out);
}

// Round 19
// 80.337 us; speedup vs baseline: 1.1158x; 1.0153x over previous
//
#include <hip/hip_runtime.h>
#include <math.h>

#define BB 128
#define HH 768
#define KQ 32768
#define PCAP 18432  // max positives per row staged in LDS
#define NB 4096     // histogram bins
#define CCAP 512    // candidate cap per target bin

constexpr float TINV = 1.0f / 0.07f;

typedef __attribute__((ext_vector_type(8))) short short8;
typedef __attribute__((ext_vector_type(4))) float f32x4;
typedef __attribute__((address_space(3))) void lds_void;
typedef const __attribute__((address_space(1))) void gbl_void;

__device__ __forceinline__ unsigned short f2bf(float f) {
  unsigned u = __float_as_uint(f);
  unsigned r = u + 0x7FFFu + ((u >> 16) & 1u);  // RNE
  return (unsigned short)(r >> 16);
}
__device__ __forceinline__ float bf2f(unsigned short h) {
  return __uint_as_float(((unsigned)h) << 16);
}
__device__ __forceinline__ unsigned cvtpk(float a, float b) {
  unsigned r;
  asm("v_cvt_pk_bf16_f32 %0, %1, %2" : "=v"(r) : "v"(a), "v"(b));
  return r;
}
__device__ __forceinline__ unsigned f2key(float f) {
  unsigned u = __float_as_uint(f);
  return u ^ (unsigned)(((int)u >> 31) | 0x80000000);
}
__device__ __forceinline__ float key2f(unsigned k) {
  unsigned u = (k & 0x80000000u) ? (k & 0x7FFFFFFFu) : ~k;
  return __uint_as_float(u);
}
__device__ __forceinline__ unsigned long long shfl_down_u64(unsigned long long v, int o) {
  unsigned lo = (unsigned)v, hi = (unsigned)(v >> 32);
  lo = __shfl_down(lo, o);
  hi = __shfl_down(hi, o);
  return ((unsigned long long)hi << 32) | lo;
}
__device__ __forceinline__ void gl16(const unsigned short* g, unsigned short* l) {
  __builtin_amdgcn_global_load_lds((gbl_void*)g, (lds_void*)l, 16, 0, 0);
}

// prep: bid<432 -> transpose W{0,1,2} (768x768 f32) into Wt (bf16, [n][k]);
//       bid>=432 -> pooled f32 -> bf16. Block 0 zeroes out[0].
__global__ __launch_bounds__(256) void prep_kernel(
    const float* __restrict__ W0, const float* __restrict__ W1,
    const float* __restrict__ W2, const float* __restrict__ pooled,
    unsigned short* __restrict__ Wt0, unsigned short* __restrict__ Wt1,
    unsigned short* __restrict__ Wt2, unsigned short* __restrict__ pooledb,
    float* __restrict__ out) {
  const int bid = blockIdx.x, tid = threadIdx.x;
  if (bid == 0 && tid == 0) out[0] = 0.0f;
  if (bid < 432) {
    const float* W = (bid < 144) ? W0 : (bid < 288 ? W1 : W2);
    unsigned short* Wt = (bid < 144) ? Wt0 : (bid < 288 ? Wt1 : Wt2);
    const int t = bid % 144;
    const int k0 = (t / 12) * 64, n0 = (t % 12) * 64;
    __shared__ float Ls[64][65];
    const int r = tid >> 4, c4 = (tid & 15) * 4;
#pragma unroll
    for (int i = 0; i < 4; ++i) {
      const int rr = r + i * 16;
      const float4 v = *reinterpret_cast<const float4*>(W + (size_t)(k0 + rr) * HH + n0 + c4);
      Ls[rr][c4 + 0] = v.x; Ls[rr][c4 + 1] = v.y;
      Ls[rr][c4 + 2] = v.z; Ls[rr][c4 + 3] = v.w;
    }
    __syncthreads();
#pragma unroll
    for (int i = 0; i < 4; ++i) {
      const int rn = r + i * 16;  // n-local
      ushort4 o;
      o.x = f2bf(Ls[c4 + 0][rn]);
      o.y = f2bf(Ls[c4 + 1][rn]);
      o.z = f2bf(Ls[c4 + 2][rn]);
      o.w = f2bf(Ls[c4 + 3][rn]);
      *reinterpret_cast<ushort4*>(Wt + (size_t)(n0 + rn) * HH + k0 + c4) = o;
    }
  } else {
    const int idx = (bid - 432) * 1024 + tid * 4;
    const float4 v = *reinterpret_cast<const float4*>(pooled + idx);
    ushort4 o;
    o.x = f2bf(v.x); o.y = f2bf(v.y); o.z = f2bf(v.z); o.w = f2bf(v.w);
    *reinterpret_cast<ushort4*>(pooledb + idx) = o;
  }
}

// head2: barrier-minimal head GEMM. Out[r0..r0+64)[n0..n0+128) =
//   act(A[64x768] @ Wt^T + bias). A-half staged ENTIRELY to LDS (96 KB,
//   one vmcnt(0)+barrier), then pure barrier-free MFMA with B streamed
//   from L2-resident Wt. Compiler schedules freely (no asm).
__device__ __forceinline__ void head2_core(
    unsigned short (*Al)[64 * 64], const unsigned short* __restrict__ A,
    const unsigned short* __restrict__ Wt, const float* __restrict__ bias,
    unsigned short* __restrict__ Out, bool do_tanh, int r0, int n0, int tid) {
  const int lane = tid & 63, wid = tid >> 6;
  const int a_r = lane & 15, a_kq = lane >> 4;

  // stage all 12 chunks: per wave per chunk 2 gl16 (8 rows x 64k each)
  int asrc[2], adst[2];
#pragma unroll
  for (int j = 0; j < 2; ++j) {
    const int rr = wid * 16 + j * 8 + (lane >> 3);  // local row 0..63
    const int kb = (lane & 7) ^ (rr & 7);
    asrc[j] = (r0 + rr) * HH + kb * 8;
    adst[j] = (wid * 16 + j * 8) * 64;
  }
#pragma unroll
  for (int c = 0; c < 12; ++c)
#pragma unroll
    for (int j = 0; j < 2; ++j)
      gl16(A + c * 64 + asrc[j], &Al[c][adst[j]]);
  asm volatile("s_waitcnt vmcnt(0)" ::: "memory");
  __builtin_amdgcn_s_barrier();

  // compute: wave owns cols [n0 + wid*32, +32), acc[4 m][2 nf]
  const unsigned short* __restrict__ bp0 =
      Wt + (size_t)(n0 + wid * 32 + a_r) * HH + a_kq * 8;
  const unsigned short* __restrict__ bp1 = bp0 + (size_t)16 * HH;
  int aslot[2];
#pragma unroll
  for (int st = 0; st < 2; ++st) aslot[st] = (((st * 4 + a_kq) ^ (a_r & 7)) << 3);

  f32x4 acc[4][2];
#pragma unroll
  for (int m = 0; m < 4; ++m)
#pragma unroll
    for (int n = 0; n < 2; ++n) acc[m][n] = (f32x4){0.f, 0.f, 0.f, 0.f};

#pragma unroll
  for (int s = 0; s < 24; ++s) {
    const short8 b0 = *reinterpret_cast<const short8*>(bp0 + s * 32);
    const short8 b1 = *reinterpret_cast<const short8*>(bp1 + s * 32);
    const int c = s >> 1;
    const int sl = aslot[s & 1];
#pragma unroll
    for (int m = 0; m < 4; ++m) {
      const short8 aa =
          *reinterpret_cast<const short8*>(&Al[c][(m * 16 + a_r) * 64 + sl]);
      acc[m][0] = __builtin_amdgcn_mfma_f32_16x16x32_bf16(aa, b0, acc[m][0], 0, 0, 0);
      acc[m][1] = __builtin_amdgcn_mfma_f32_16x16x32_bf16(aa, b1, acc[m][1], 0, 0, 0);
    }
  }

#pragma unroll
  for (int n = 0; n < 2; ++n) {
    const int col = n0 + wid * 32 + n * 16 + a_r;
    const float bvl = bias[col];
#pragma unroll
    for (int m = 0; m < 4; ++m)
#pragma unroll
      for (int r = 0; r < 4; ++r) {
        float v = acc[m][n][r] + bvl;
        if (do_tanh) v = tanhf(v);
        Out[(size_t)(r0 + m * 16 + a_kq * 4 + r) * HH + col] = f2bf(v);
      }
  }
}

// grid (6, 2, 2): x=col-group(128), y=row-half(64), z=head.
__global__ __launch_bounds__(256) void heads_mfma(
    const unsigned short* __restrict__ pooledb,
    const unsigned short* __restrict__ Wt0, const float* __restrict__ b0,
    unsigned short* __restrict__ H1b,
    const unsigned short* __restrict__ Wt1, const float* __restrict__ b1,
    unsigned short* __restrict__ H2b) {
  __shared__ unsigned short Al[12][64 * 64];  // 96 KB
  const int z = blockIdx.z;
  head2_core(Al, pooledb, z ? Wt1 : Wt0, z ? b1 : b0, z ? H2b : H1b, true,
             blockIdx.y * 64, blockIdx.x * 128, threadIdx.x);
}

// grid (6, 2): Yb = H2b @ Wt2^T + b (no act).
__global__ __launch_bounds__(256) void out_gemm(
    const unsigned short* __restrict__ H2b, const unsigned short* __restrict__ Wt2,
    const float* __restrict__ b2v, unsigned short* __restrict__ Yb) {
  __shared__ unsigned short Al[12][64 * 64];  // 96 KB
  head2_core(Al, H2b, Wt2, b2v, Yb, false, blockIdx.y * 64, blockIdx.x * 128,
             threadIdx.x);
}

// cos GEMM v16 (R16/R18, best): 256 thr, quad-buffered counted-vmcnt, bf16 C.
__global__ __launch_bounds__(256, 2) void cos_gemm_mfma(
    const unsigned short* __restrict__ qh, const float* __restrict__ FQ,
    unsigned short* __restrict__ Cb) {
  __shared__ unsigned short Abuf[4][128 * 64];  // 4 x 16 KB
  const int tid = threadIdx.x;
  const int lane = tid & 63, wid = tid >> 6;
  const int bid = blockIdx.x;
  const int swz = (bid & 7) * 64 + (bid >> 3);
  const int q0 = swz * 64;
  const int a_r = lane & 15, a_kq = lane >> 4;

  int asrc[4], adst[4];
#pragma unroll
  for (int j = 0; j < 4; ++j) {
    const int rr = (wid * 4 + j) * 8 + (lane >> 3);
    const int kb = (lane & 7) ^ (rr & 7);
    asrc[j] = rr * HH + kb * 8;
    adst[j] = (wid * 4 + j) * 512;
  }
  const float* __restrict__ bptr = FQ + (size_t)(q0 + wid * 16 + a_r) * HH + a_kq * 8;
  int aslot[2];
#pragma unroll
  for (int st = 0; st < 2; ++st) aslot[st] = (((st * 4 + a_kq) ^ (a_r & 7)) << 3);

  f32x4 acc[8];
#pragma unroll
  for (int m = 0; m < 8; ++m) acc[m] = (f32x4){0.f, 0.f, 0.f, 0.f};

#pragma unroll
  for (int j = 0; j < 4; ++j) gl16(qh + asrc[j], &Abuf[0][adst[j]]);
  __builtin_amdgcn_sched_barrier(0);
#pragma unroll
  for (int j = 0; j < 4; ++j) gl16(qh + 64 + asrc[j], &Abuf[1][adst[j]]);
  __builtin_amdgcn_sched_barrier(0);
#pragma unroll
  for (int j = 0; j < 4; ++j) gl16(qh + 128 + asrc[j], &Abuf[2][adst[j]]);
  __builtin_amdgcn_sched_barrier(0);
  float4 bv[8][2];
#pragma unroll
  for (int p = 0; p < 8; ++p) {
    bv[p][0] = *reinterpret_cast<const float4*>(bptr + p * 32);
    bv[p][1] = *reinterpret_cast<const float4*>(bptr + p * 32 + 4);
  }
  __builtin_amdgcn_sched_barrier(0);
  asm volatile("s_waitcnt vmcnt(24)" ::: "memory");  // G0 retired
  __builtin_amdgcn_s_barrier();
  __builtin_amdgcn_sched_barrier(0);

#pragma unroll
  for (int c = 0; c < 12; ++c) {
    if (c + 3 < 12) {
#pragma unroll
      for (int j = 0; j < 4; ++j)
        gl16(qh + (c + 3) * 64 + asrc[j], &Abuf[(c + 3) & 3][adst[j]]);
    }
    __builtin_amdgcn_sched_barrier(0);  // pin gl16 batch above B/MFMA region
    const unsigned short* __restrict__ Ab = Abuf[c & 3];
#pragma unroll
    for (int st = 0; st < 2; ++st) {
      const int s = c * 2 + st;
      const float4 v0 = bv[s & 7][0], v1 = bv[s & 7][1];
      if (s + 8 < 24) {
        bv[s & 7][0] = *reinterpret_cast<const float4*>(bptr + (s + 8) * 32);
        bv[s & 7][1] = *reinterpret_cast<const float4*>(bptr + (s + 8) * 32 + 4);
      }
      union { short8 s8; unsigned u[4]; } cb;
      cb.u[0] = cvtpk(v0.x, v0.y);
      cb.u[1] = cvtpk(v0.z, v0.w);
      cb.u[2] = cvtpk(v1.x, v1.y);
      cb.u[3] = cvtpk(v1.z, v1.w);
      const short8 bb = cb.s8;
      const int sl = aslot[st];
#pragma unroll
      for (int m = 0; m < 8; ++m) {
        const short8 aa =
            *reinterpret_cast<const short8*>(&Ab[(m * 16 + a_r) * 64 + sl]);
        acc[m] = __builtin_amdgcn_mfma_f32_16x16x32_bf16(aa, bb, acc[m], 0, 0, 0);
      }
    }
    if (c < 11) {
      __builtin_amdgcn_sched_barrier(0);  // pin B/MFMA region above the wait
      if (c == 0)      asm volatile("s_waitcnt vmcnt(28)" ::: "memory");
      else if (c == 1) asm volatile("s_waitcnt vmcnt(32)" ::: "memory");
      else if (c <= 7) asm volatile("s_waitcnt vmcnt(20)" ::: "memory");
      else if (c == 8) asm volatile("s_waitcnt vmcnt(16)" ::: "memory");
      else if (c == 9) asm volatile("s_waitcnt vmcnt(8)" ::: "memory");
      else             asm volatile("s_waitcnt vmcnt(0)" ::: "memory");
      __builtin_amdgcn_s_barrier();
      __builtin_amdgcn_sched_barrier(0);
    }
  }

  const int ccol = q0 + wid * 16 + a_r;
#pragma unroll
  for (int m = 0; m < 8; ++m)
#pragma unroll
    for (int r = 0; r < 4; ++r)
      Cb[(size_t)(m * 16 + a_kq * 4 + r) * KQ + ccol] = f2bf(acc[m][r]);
}

// Self-contained select (bf16 C rows) + folded cls-CE for row b.
__global__ __launch_bounds__(1024) void select_kernel(
    const unsigned short* __restrict__ Cb, const unsigned short* __restrict__ Yb,
    const unsigned short* __restrict__ H1b, const float* __restrict__ W2,
    const float* __restrict__ cb2, const int* __restrict__ labels,
    const int* __restrict__ lq, float* __restrict__ out) {
  const int b = blockIdx.x;
  const int tid = threadIdx.x;
  const int lane = tid & 63, wid = tid >> 6;
  const unsigned short* __restrict__ row = Cb + (size_t)b * KQ;
  const int lab = labels[b];

  __shared__ __align__(16) unsigned poskeys[PCAP];
  __shared__ unsigned hist[NB + 1];
  __shared__ unsigned cand[3][CCAP];
  __shared__ int candn[3];
  __shared__ float redm[16], reds[16], redmin[16], redmax[16];
  __shared__ int redn[16];
  __shared__ unsigned wsum[16];
  __shared__ float shc0[16], shc1[16];
  __shared__ int abin[3], acnt[3];
  __shared__ unsigned akey[3];
  __shared__ unsigned long long accg;
  __shared__ float gs0, gsm, s_logE, s_vmin, s_vmax, s_rs;
  __shared__ float ssq[2];
  __shared__ int s_cnt, s_m, has01;

  if (tid == 0) { s_cnt = 0; gs0 = 0.f; gsm = 0.f; accg = 0ull; has01 = 0; }
  if (tid < 3) candn[tid] = 0;

  // ---------- folded cls CE partials for row b ----------
  float cp0 = 0.f, cp1 = 0.f;
  if (tid < HH) {
    const float v = bf2f(H1b[(size_t)b * HH + tid]);
    cp0 = v * W2[tid * 2 + 0];
    cp1 = v * W2[tid * 2 + 1];
  }
#pragma unroll
  for (int o = 32; o; o >>= 1) {
    cp0 += __shfl_down(cp0, o);
    cp1 += __shfl_down(cp1, o);
  }
  if (lane == 0) { shc0[wid] = cp0; shc1[wid] = cp1; }

  // ---------- row scale rs = 1/||Yb[b]|| ----------
  float ssl = 0.f;
  if (tid < 96) {
    const short8 y8 =
        *reinterpret_cast<const short8*>(Yb + (size_t)b * HH + tid * 8);
#pragma unroll
    for (int e = 0; e < 8; ++e) {
      const float v = bf2f((unsigned short)y8[e]);
      ssl = fmaf(v, v, ssl);
    }
  }
#pragma unroll
  for (int o = 32; o; o >>= 1) ssl += __shfl_down(ssl, o);
  if (lane == 0 && wid < 2) ssq[wid] = ssl;
  __syncthreads();
  if (tid == 0) s_rs = rsqrtf(ssq[0] + ssq[1]);
  __syncthreads();
  const float rs = s_rs;

  const int base = tid << 5;
  unsigned qm = 0u;
  {
    const int4* __restrict__ lq4 = reinterpret_cast<const int4*>(lq + base);
#pragma unroll
    for (int u = 0; u < 8; ++u) {
      const int4 q = lq4[u];
      qm |= (unsigned)(q.x != 0) << (u * 4 + 0);
      qm |= (unsigned)(q.y != 0) << (u * 4 + 1);
      qm |= (unsigned)(q.z != 0) << (u * 4 + 2);
      qm |= (unsigned)(q.w != 0) << (u * 4 + 3);
    }
  }
  if (tid < BB) atomicOr(&has01, 1 << labels[tid]);
  const unsigned pmask = lab ? qm : ~qm;
  float va[32];
#pragma unroll
  for (int u = 0; u < 4; ++u) {
    const short8 y8 = *reinterpret_cast<const short8*>(row + base + (u << 3));
#pragma unroll
    for (int e = 0; e < 8; ++e)
      va[(u << 3) + e] = bf2f((unsigned short)y8[e]) * rs;
  }
  float mneg = -3.0e38f, sneg = 0.f, vmin = 3.0e38f, vmax = -3.0e38f;
#pragma unroll
  for (int j = 0; j < 32; ++j) {
    if ((pmask >> j) & 1u) {
      vmin = fminf(vmin, va[j]);
      vmax = fmaxf(vmax, va[j]);
    } else {
      mneg = fmaxf(mneg, va[j] * TINV);
    }
  }
#pragma unroll
  for (int j = 0; j < 32; ++j) {
    if (!((pmask >> j) & 1u)) sneg += __expf(va[j] * TINV - mneg);
  }
  int nc = __popc(qm);
#pragma unroll
  for (int o = 32; o; o >>= 1) {
    const float mo = __shfl_down(mneg, o), so = __shfl_down(sneg, o);
    const float M = fmaxf(mneg, mo);
    sneg = sneg * __expf(mneg - M) + so * __expf(mo - M);
    mneg = M;
    vmin = fminf(vmin, __shfl_down(vmin, o));
    vmax = fmaxf(vmax, __shfl_down(vmax, o));
    nc += __shfl_down(nc, o);
  }
  if (lane == 0) {
    redm[wid] = mneg; reds[wid] = sneg; redmin[wid] = vmin; redmax[wid] = vmax;
    redn[wid] = nc;
  }

  const int np = __popc(pmask);
  unsigned incl = (unsigned)np;
#pragma unroll
  for (int o = 1; o < 64; o <<= 1) {
    const unsigned t = __shfl_up(incl, o);
    if (lane >= o) incl += t;
  }
  const unsigned excl = incl - (unsigned)np;
  const unsigned wtot = __shfl(incl, 63);
  unsigned wbase = 0u;
  if (lane == 63) wbase = (unsigned)atomicAdd(&s_cnt, (int)wtot);
  wbase = __shfl(wbase, 63);
  const int ofs = (int)(wbase + excl);
  if (ofs + np <= PCAP) {
#pragma unroll
    for (int j = 0; j < 32; ++j) {
      if ((pmask >> j) & 1u)
        poskeys[ofs + __popc(pmask & ((1u << j) - 1u))] = f2key(va[j]);
    }
  }
  __syncthreads();

  const int P = s_cnt;
  if (tid == 0) {
    float M = redm[0], S = 0.f;
    float mn = redmin[0], mx = redmax[0];
    int n1 = 0;
    for (int w = 1; w < 16; ++w) {
      M = fmaxf(M, redm[w]);
      mn = fminf(mn, redmin[w]);
      mx = fmaxf(mx, redmax[w]);
    }
    for (int w = 0; w < 16; ++w) { S += reds[w] * __expf(redm[w] - M); n1 += redn[w]; }
    s_logE = M + logf(S);
    s_vmin = mn;
    s_vmax = mx;
    int mm = 0x7fffffff;
    if (has01 & 1) mm = min(mm, KQ - n1);
    if (has01 & 2) mm = min(mm, n1);
    s_m = mm;
  }
  if (tid < ((4 - (P & 3)) & 3)) poskeys[P + tid] = 0u;
  for (int i = tid; i < NB + 1; i += 1024) hist[i] = 0u;
  __syncthreads();

  const float cE = s_logE;
  const int m = s_m;
  const float vmn = s_vmin;
  const float scale = (float)NB * (1.0f - 1e-6f) / fmaxf(s_vmax - vmn, 1e-30f);
  auto key2bin = [&](unsigned k) {
    int bn = (int)((key2f(k) - vmn) * scale);
    return bn < 0 ? 0 : (bn > NB - 1 ? NB - 1 : bn);
  };

  for (int i = tid; i < P; i += 1024) atomicAdd(&hist[key2bin(poskeys[i])], 1u);
  __syncthreads();

  const int t4 = tid << 2;
  const unsigned h0 = hist[t4], h1 = hist[t4 + 1], h2 = hist[t4 + 2], h3 = hist[t4 + 3];
  const unsigned part = h0 + h1 + h2 + h3;
  unsigned sinc = part;
#pragma unroll
  for (int o = 1; o < 64; o <<= 1) {
    const unsigned t = __shfl_up(sinc, o);
    if (lane >= o) sinc += t;
  }
  if (lane == 63) wsum[wid] = sinc;
  __syncthreads();
  unsigned woff = 0;
  for (int w = 0; w < wid; ++w) woff += wsum[w];
  const unsigned exb = woff + sinc - part;
  hist[t4] = exb; hist[t4 + 1] = exb + h0; hist[t4 + 2] = exb + h0 + h1;
  hist[t4 + 3] = exb + h0 + h1 + h2;
  if (tid == 1023) hist[NB] = exb + part;
  __syncthreads();

  const int rt0 = 25, rt1 = m - 25, rt2 = m;
  const unsigned idx0 = (unsigned)(P - rt0), idx1 = (unsigned)(P - rt1), idx2 = (unsigned)(P - rt2);
#pragma unroll
  for (int i = 0; i < 4; ++i) {
    const int bb = t4 + i;
    const unsigned pb = hist[bb], pb1 = hist[bb + 1];
    if (pb <= idx0 && idx0 < pb1) { abin[0] = bb; acnt[0] = P - (int)pb1; }
    if (pb <= idx1 && idx1 < pb1) { abin[1] = bb; acnt[1] = P - (int)pb1; }
    if (pb <= idx2 && idx2 < pb1) { abin[2] = bb; acnt[2] = P - (int)pb1; }
  }
  __syncthreads();

  const int tb0 = abin[0], tb1 = abin[1], tb2 = abin[2];
  for (int i = tid; i < P; i += 1024) {
    const unsigned k = poskeys[i];
    const int bn = key2bin(k);
    if (bn == tb0) { const int p = atomicAdd(&candn[0], 1); if (p < CCAP) cand[0][p] = k; }
    if (bn == tb1) { const int p = atomicAdd(&candn[1], 1); if (p < CCAP) cand[1][p] = k; }
    if (bn == tb2) { const int p = atomicAdd(&candn[2], 1); if (p < CCAP) cand[2][p] = k; }
  }
  __syncthreads();

  if (wid < 3) {
    const int j = wid;
    const int rts[3] = {rt0, rt1, rt2};
    const int cnt = candn[j] < CCAP ? candn[j] : CCAP;
    const int rr = rts[j] - acnt[j];
    for (int i = lane; i < cnt; i += 64) {
      const unsigned k = cand[j][i];
      int gt = 0, eq = 0;
      for (int q = 0; q < cnt; ++q) {
        const unsigned kq = cand[j][q];
        gt += (kq > k);
        eq += (kq == k);
      }
      if (gt < rr && rr <= gt + eq) akey[j] = k;
    }
  }
  __syncthreads();

  const unsigned a0 = akey[0], a1 = akey[1], a2 = akey[2];
  const int P4c = (P + 3) >> 2;
  const uint4* __restrict__ pk4 = reinterpret_cast<const uint4*>(poskeys);

  float s0 = 0.f, sm = 0.f;
  unsigned q0c = 0, q1c = 0, q2c = 0;
  for (int i = tid; i < P4c; i += 1024) {
    const uint4 kv = pk4[i];
    const unsigned ks[4] = {kv.x, kv.y, kv.z, kv.w};
#pragma unroll
    for (int j = 0; j < 4; ++j) {
      const unsigned k = ks[j];
      if (k > a2) {
        ++q2c;
        const bool top = (k > a0), mid = (k <= a1);
        if (k > a1) ++q1c;
        if (top) ++q0c;
        if (top || mid) {
          const float a = key2f(k) * TINV;
          const float d = cE - a;
          const float fv = fmaxf(d, 0.f) + log1pf(__expf(-fabsf(d)));
          if (top) s0 += fv;
          if (mid) sm += fv;
        }
      }
    }
  }
  unsigned long long pc = (unsigned long long)q0c |
                          ((unsigned long long)q1c << 20) |
                          ((unsigned long long)q2c << 40);
#pragma unroll
  for (int o = 32; o; o >>= 1) {
    s0 += __shfl_down(s0, o);
    sm += __shfl_down(sm, o);
    pc += shfl_down_u64(pc, o);
  }
  if (lane == 0) {
    atomicAdd(&gs0, s0);
    atomicAdd(&gsm, sm);
    atomicAdd(&accg, pc);
  }
  __syncthreads();
  if (tid == 0) {
    const unsigned long long t = accg;
    const float C0 = (float)(unsigned)(t & 0xFFFFFu);
    const float C1 = (float)(unsigned)((t >> 20) & 0xFFFFFu);
    const float C2 = (float)(unsigned)((t >> 40) & 0xFFFFFu);
    auto fval = [&](unsigned kk) {
      const float a = key2f(kk) * TINV;
      const float d = cE - a;
      return fmaxf(d, 0.f) + log1pf(__expf(-fabsf(d)));
    };
    const float f0 = fval(a0), f1 = fval(a1), f2 = fval(a2);
    const float top25 = gs0 + (25.0f - C0) * f0;
    const float mid = gsm + ((float)m - C2) * f2 - ((float)(m - 25) - C1) * f1;
    // folded cls CE for row b
    float l0 = cb2[0], l1 = cb2[1];
    for (int w = 0; w < 16; ++w) { l0 += shc0[w]; l1 += shc1[w]; }
    const float mx = fmaxf(l0, l1), mn = fminf(l0, l1);
    const float lse = mx + log1pf(__expf(mn - mx));
    const float ce = lse - (lab ? l1 : l0);
    atomicAdd(out, 0.9f * ce * (1.0f / 128.0f) +
                       0.1f * (top25 + mid) * (1.0f / 6400.0f));
  }
}

extern "C" void kernel_launch(void* const* d_in, const int* in_sizes, int n_in,
                              void* d_out, int out_size, void* d_ws, size_t ws_size,
                              hipStream_t stream) {
  const float* pooled = (const float*)d_in[0];
  const int* labels = (const int*)d_in[1];
  const float* fq = (const float*)d_in[2];
  const int* lq = (const int*)d_in[3];
  const float* cls_dw = (const float*)d_in[4];
  const float* cls_db = (const float*)d_in[5];
  const float* cls_ow = (const float*)d_in[6];
  const float* cls_ob = (const float*)d_in[7];
  const float* con_dw = (const float*)d_in[8];
  const float* con_db = (const float*)d_in[9];
  const float* con_ow = (const float*)d_in[10];
  const float* con_ob = (const float*)d_in[11];
  float* out = (float*)d_out;

  // Layout: [Cb: 8MB bf16][Yb|H1b|H2b|pooledb: 4x192KB]. Wt0..2 (bf16 768^2
  // each, 3.4MB total) alias the FRONT of Cb — dead before cos writes Cb.
  float* ws = (float*)d_ws;
  unsigned short* Cb = (unsigned short*)ws;                 // 128*32768 bf16
  unsigned short* Yb = Cb + (size_t)BB * KQ;
  unsigned short* H1b = Yb + 98304;
  unsigned short* H2b = H1b + 98304;
  unsigned short* pooledb = H2b + 98304;
  unsigned short* Wt0 = Cb;                                 // aliases Cb
  unsigned short* Wt1 = Wt0 + 589824;
  unsigned short* Wt2 = Wt1 + 589824;

  prep_kernel<<<528, 256, 0, stream>>>(cls_dw, con_dw, con_ow, pooled,
                                       Wt0, Wt1, Wt2, pooledb, out);
  heads_mfma<<<dim3(6, 2, 2), 256, 0, stream>>>(pooledb, Wt0, cls_db, H1b,
                                                Wt1, con_db, H2b);
  out_gemm<<<dim3(6, 2), 256, 0, stream>>>(H2b, Wt2, con_ob, Yb);
  cos_gemm_mfma<<<512, 256, 0, stream>>>(Yb, fq, Cb);
  select_kernel<<<128, 1024, 0, stream>>>(Cb, Yb, H1b, cls_ow, cls_ob,
                                          labels, lq, out);
}